// Round 6
// baseline (231.080 us; speedup 1.0000x reference)
//
#include <hip/hip_runtime.h>

// Problem geometry (fixed by the reference)
#define SPATIAL 32768            // D*H*W
#define NB 4
#define CDIM 128
#define KCODES 1024
#define NROWS (NB * SPATIAL)     // 131072

// Output layout in d_out (all float32, concatenated in return order)
#define Q_SIZE (NB * CDIM * SPATIAL)     // 16777216
#define LOSS_OFF Q_SIZE
#define IDX_OFF (Q_SIZE + 1)
#define ESUM_OFF (IDX_OFF + NROWS)
#define EMB_OFF (ESUM_OFF + 256)

#define TCODES 64                // codes per tile
#define NT (KCODES / TCODES)     // 16 tiles
#define MARGIN 0.10f
#define CAP 8192
#define FINF 3.4e38f
#define LSCALE 1048576.0f        // 2^20 fixed-point for deterministic loss

typedef _Float16 half8 __attribute__((ext_vector_type(8)));
typedef float f32x4 __attribute__((ext_vector_type(4)));

static __device__ __forceinline__ void gload16(const uint4* g, uint4* l) {
    __builtin_amdgcn_global_load_lds(
        (const __attribute__((address_space(1))) unsigned int*)g,
        (__attribute__((address_space(3))) unsigned int*)l, 16, 0, 0);
}

// ---- prep: emb -> packed, pre-swizzled fp16 tiles of 64 codes + exact ||e||^2
// Bpk (uint4 granules of 8 fp16): [(t*64 + cl)*16 + (g ^ (cl&15))]
__global__ __launch_bounds__(128) void prep_kernel(const float* __restrict__ emb,
                                                   uint4* __restrict__ Bpk,
                                                   float* __restrict__ esq) {
    int k = blockIdx.x * 128 + threadIdx.x;
    if (k >= KCODES) return;
    int t = k >> 6, cl = k & 63;
    const float* e = emb + (size_t)k * CDIM;
    uint4* bp = Bpk + ((size_t)t * TCODES + cl) * 16;
    float s = 0.f;
#pragma unroll
    for (int g = 0; g < 16; g++) {
        unsigned hp[4];
#pragma unroll
        for (int p = 0; p < 4; p++) {
            float v0 = e[g * 8 + 2 * p + 0];
            float v1 = e[g * 8 + 2 * p + 1];
            union { _Float16 h[2]; unsigned u; } pk;
            pk.h[0] = (_Float16)v0;
            pk.h[1] = (_Float16)v1;
            hp[p] = pk.u;
            s = fmaf(v0, v0, s);
            s = fmaf(v1, v1, s);
        }
        bp[g ^ (cl & 15)] = make_uint4(hp[0], hp[1], hp[2], hp[3]);
    }
    esq[k] = s;
}

// ---- scoring + fused emit: fp16 single-pass, 3-deep counted-vmcnt pipeline --
__global__ __launch_bounds__(256, 3) void score_kernel(const float* __restrict__ in,
                                                       const uint4* __restrict__ Bpk,
                                                       const float* __restrict__ esq,
                                                       const float* __restrict__ emb,
                                                       float* __restrict__ out,
                                                       int* __restrict__ flag_list,
                                                       int* __restrict__ flag_cnt,
                                                       unsigned long long* __restrict__ loss_acc) {
    __shared__ uint4 BB[3][TCODES * 16];     // 3 x 16 KB ring
    __shared__ float b1L[128];
    __shared__ int   i1L[128];
    __shared__ float xsqL[128];
    __shared__ unsigned long long redL[16];

    const int tid = threadIdx.x;
    const int lane = tid & 63;
    const int w = tid >> 6;              // wave 0..3, owns rows w*32..w*32+31
    const int l15 = lane & 15;
    const int lg = lane >> 4;
    const int row0 = blockIdx.x * 128;
    const int b = row0 >> 15;
    const int sbase = (row0 & (SPATIAL - 1)) + w * 32;

#define STAGE(tt, bb)                                                     \
    do {                                                                  \
        const uint4* src_ = Bpk + (size_t)(tt) * 1024;                    \
        _Pragma("unroll")                                                 \
        for (int i_ = 0; i_ < 4; i_++)                                    \
            gload16(src_ + i_ * 256 + tid, &BB[bb][i_ * 256 + tid]);      \
    } while (0)

    STAGE(0, 0);   // tiles 0,1 DMA overlap the A-load below
    STAGE(1, 1);

    // ---- A fragments in registers: fp16, all K=128; exact ||x||^2 (fp32)
    half8 Af[8];                          // index [kk*2 + m]
    float xsq[2] = {0.f, 0.f};
    {
        const float* xb = in + (size_t)b * CDIM * SPATIAL;
#pragma unroll
        for (int kk = 0; kk < 4; kk++)
#pragma unroll
            for (int m = 0; m < 2; m++) {
                int srow = sbase + m * 16 + l15;
                union { unsigned u[4]; half8 h; } pk;
#pragma unroll
                for (int p = 0; p < 4; p++) {
                    int c0 = kk * 32 + lg * 8 + 2 * p;
                    float v0 = xb[(size_t)(c0 + 0) * SPATIAL + srow];
                    float v1 = xb[(size_t)(c0 + 1) * SPATIAL + srow];
                    union { _Float16 h[2]; unsigned u; } q;
                    q.h[0] = (_Float16)v0;
                    q.h[1] = (_Float16)v1;
                    pk.u[p] = q.u;
                    xsq[m] = fmaf(v0, v0, xsq[m]);
                    xsq[m] = fmaf(v1, v1, xsq[m]);
                }
                Af[kk * 2 + m] = pk.h;
            }
    }
    // reduce ||x||^2 over the 4 lg channel-groups
#pragma unroll
    for (int m = 0; m < 2; m++) {
        xsq[m] += __shfl_xor(xsq[m], 16);
        xsq[m] += __shfl_xor(xsq[m], 32);
    }
    if (lg == 0) {
        xsqL[w * 32 + l15] = xsq[0];
        xsqL[w * 32 + 16 + l15] = xsq[1];
    }

    float b1[8], b2[8];
    int i1[8];
#pragma unroll
    for (int i = 0; i < 8; i++) { b1[i] = FINF; b2[i] = FINF; i1[i] = 0; }

    for (int t = 0; t < NT; t++) {
        // tile t's DMA (issued >=2 iterations ago) must have landed; keep
        // tile t+1 (4 loads) in flight. Never vmcnt(0) mid-loop.
        if (t == NT - 1) asm volatile("s_waitcnt vmcnt(0)" ::: "memory");
        else             asm volatile("s_waitcnt vmcnt(4)" ::: "memory");
        __builtin_amdgcn_s_barrier();     // all waves' tile-t data visible;
                                          // all waves done reading buf (t+2)%3
        if (t + 2 < NT) STAGE(t + 2, (t + 2) % 3);

        const half8* Bs = reinterpret_cast<const half8*>(BB[t % 3]);
        f32x4 acc[2][4];
#pragma unroll
        for (int m = 0; m < 2; m++)
#pragma unroll
            for (int n = 0; n < 4; n++) acc[m][n] = (f32x4){0.f, 0.f, 0.f, 0.f};

#pragma unroll
        for (int kk = 0; kk < 4; kk++) {
            int phys = (kk * 4 + lg) ^ l15;
            half8 bv[4];
#pragma unroll
            for (int n = 0; n < 4; n++) bv[n] = Bs[(n * 16 + l15) * 16 + phys];
#pragma unroll
            for (int m = 0; m < 2; m++)
#pragma unroll
                for (int n = 0; n < 4; n++)
                    acc[m][n] = __builtin_amdgcn_mfma_f32_16x16x32_f16(Af[kk * 2 + m], bv[n], acc[m][n], 0, 0, 0);
        }

        // epilogue: s = ||e||^2 - 2*dot ; top1(val,idx) + top2(val)
#pragma unroll
        for (int n = 0; n < 4; n++) {
            int col = t * TCODES + n * 16 + l15;
            float ev = esq[col];
#pragma unroll
            for (int m = 0; m < 2; m++)
#pragma unroll
                for (int r = 0; r < 4; r++) {
                    float sv = fmaf(-2.f, acc[m][n][r], ev);
                    int slot = m * 4 + r;
                    bool c = sv < b1[slot];
                    b2[slot] = fminf(fmaxf(sv, b1[slot]), b2[slot]);   // med3
                    b1[slot] = fminf(sv, b1[slot]);
                    i1[slot] = c ? col : i1[slot];
                }
        }
    }
#undef STAGE

    // butterfly merge across the 16 col-lanes
#pragma unroll
    for (int j = 1; j < 16; j <<= 1) {
#pragma unroll
        for (int slot = 0; slot < 8; slot++) {
            float ob1 = __shfl_xor(b1[slot], j);
            float ob2 = __shfl_xor(b2[slot], j);
            int   oi  = __shfl_xor(i1[slot], j);
            bool take = (ob1 < b1[slot]) || (ob1 == b1[slot] && oi < i1[slot]);
            float nb2 = fminf(fmaxf(b1[slot], ob1), fminf(b2[slot], ob2));
            b1[slot] = take ? ob1 : b1[slot];
            i1[slot] = take ? oi : i1[slot];
            b2[slot] = nb2;
        }
    }

    __syncthreads();   // xsqL visible (also separates LDS reuse)

    if (l15 == 0) {
        unsigned long long lsum = 0;
#pragma unroll
        for (int m = 0; m < 2; m++)
#pragma unroll
            for (int r = 0; r < 4; r++) {
                int slot = m * 4 + r;
                int rl = w * 32 + m * 16 + lg * 4 + r;
                b1L[rl] = b1[slot];
                i1L[rl] = i1[slot];
                float cexp = b1[slot] + xsqL[rl];          // ||e||^2-2x.e+||x||^2
                unsigned long long ci = (unsigned long long)llrintf(cexp * LSCALE);
                if (b2[slot] - b1[slot] < MARGIN) {
                    int p = atomicAdd(flag_cnt, 1);
                    if (p < CAP) { flag_list[p] = row0 + rl; ci = 0; }  // refine adds exact
                }
                lsum += ci;
            }
        redL[w * 4 + lg] = lsum;
    }
    __syncthreads();
    if (tid == 0) {
        unsigned long long s = 0;
#pragma unroll
        for (int i = 0; i < 16; i++) s += redL[i];
        atomicAdd(loss_acc, s);
    }

    // ---- fused emit: idx, quantized (gather emb[k], channel-first write)
    {
        const int rl = w * 32 + (lane & 31);
        const int row = row0 + rl;
        const int sp = (row0 & (SPATIAL - 1)) + rl;
        const int k = i1L[rl];
        const int chalf = lane >> 5;

        if (chalf == 0) out[IDX_OFF + row] = (float)k;
        const float4* ep = reinterpret_cast<const float4*>(emb + (size_t)k * CDIM + chalf * 64);
        float* qout = out + (size_t)b * CDIM * SPATIAL + (size_t)chalf * 64 * SPATIAL + sp;
#pragma unroll
        for (int i = 0; i < 16; i++) {
            float4 v = ep[i];
            qout[(size_t)(4 * i + 0) * SPATIAL] = v.x;
            qout[(size_t)(4 * i + 1) * SPATIAL] = v.y;
            qout[(size_t)(4 * i + 2) * SPATIAL] = v.z;
            qout[(size_t)(4 * i + 3) * SPATIAL] = v.w;
        }
    }
}

// ---- refine: exact fp32 rescan of flagged rows (grid-strided, conflict-free)
// One 128-thread block per flagged row. x staged in LDS (broadcast reads);
// each thread streams 8 codebook rows (L2-resident) as float4. Fixes idx,
// quantized row, and adds the exact loss contribution.
__global__ __launch_bounds__(128) void refine_kernel(const float* __restrict__ in,
                                                     const float* __restrict__ emb,
                                                     const float* __restrict__ esq,
                                                     const int* __restrict__ flag_list,
                                                     const int* __restrict__ flag_cnt,
                                                     float* __restrict__ out,
                                                     unsigned long long* __restrict__ loss_acc) {
    __shared__ float xL[CDIM];
    __shared__ float rv[128];
    __shared__ int   ri[128];

    int n = *flag_cnt; if (n > CAP) n = CAP;
    const int t = threadIdx.x;
    const float4* e4 = reinterpret_cast<const float4*>(emb);
    const float4* x4 = reinterpret_cast<const float4*>(xL);

    for (int fi = blockIdx.x; fi < n; fi += gridDim.x) {
        const int row = flag_list[fi];
        const int b = row >> 15, s = row & (SPATIAL - 1);
        const float xv = in[((size_t)b * CDIM + t) * SPATIAL + s];
        xL[t] = xv;
        __syncthreads();

        float best = FINF; int bi = 0;
#pragma unroll
        for (int j = 0; j < 8; j++) {
            const int k = j * 128 + t;
            float d0 = 0.f, d1 = 0.f, d2 = 0.f, d3 = 0.f;
#pragma unroll 8
            for (int c4 = 0; c4 < 32; c4++) {
                float4 ev = e4[(size_t)k * 32 + c4];
                float4 xx = x4[c4];              // lockstep same addr -> broadcast
                d0 = fmaf(ev.x, xx.x, d0);
                d1 = fmaf(ev.y, xx.y, d1);
                d2 = fmaf(ev.z, xx.z, d2);
                d3 = fmaf(ev.w, xx.w, d3);
            }
            float d = fmaf(-2.f, (d0 + d1) + (d2 + d3), esq[k]);
            if (d < best) { best = d; bi = k; }  // k ascending in j -> first occurrence per thread
        }
        rv[t] = best; ri[t] = bi;
        __syncthreads();
#pragma unroll
        for (int off = 64; off > 0; off >>= 1) {
            if (t < off) {
                bool take = (rv[t + off] < rv[t]) ||
                            (rv[t + off] == rv[t] && ri[t + off] < ri[t]);
                if (take) { rv[t] = rv[t + off]; ri[t] = ri[t + off]; }
            }
            __syncthreads();
        }
        const int kbest = ri[0];
        const float dbest = rv[0];
        __syncthreads();

        // exact ||x||^2 reduce
        rv[t] = xv * xv;
        __syncthreads();
#pragma unroll
        for (int off = 64; off > 0; off >>= 1) {
            if (t < off) rv[t] += rv[t + off];
            __syncthreads();
        }
        if (t == 0) {
            out[IDX_OFF + row] = (float)kbest;
            atomicAdd(loss_acc, (unsigned long long)llrintf((dbest + rv[0]) * LSCALE));
        }
        // rewrite quantized row
        out[(size_t)b * CDIM * SPATIAL + (size_t)t * SPATIAL + s] = emb[(size_t)kbest * CDIM + t];
        __syncthreads();   // before next iteration overwrites xL/rv
    }
}

// ---- finalize: fixed-point -> float loss ------------------------------------
__global__ void finalize_kernel(const unsigned long long* __restrict__ loss_acc,
                                float* __restrict__ out) {
    double s = (double)*loss_acc / (double)LSCALE;
    out[LOSS_OFF] = (float)(0.25 * s / (double)Q_SIZE);
}

extern "C" void kernel_launch(void* const* d_in, const int* in_sizes, int n_in,
                              void* d_out, int out_size, void* d_ws, size_t ws_size,
                              hipStream_t stream) {
    const float* in = (const float*)d_in[0];
    const float* emb = (const float*)d_in[1];
    float* out = (float*)d_out;

    float* esq = (float*)d_ws;                                  // 4096 f32 (pad)
    uint4* Bpk = (uint4*)(esq + 4096);                          // 16384 uint4 (256 KB)
    unsigned long long* loss_acc = (unsigned long long*)(Bpk + KCODES * 16);
    int* flag_cnt = (int*)(loss_acc + 2);
    int* flag_list = flag_cnt + 4;                              // CAP i32

    hipMemsetAsync(loss_acc, 0, 8, stream);
    hipMemsetAsync(flag_cnt, 0, sizeof(int), stream);
    hipMemsetAsync(out + ESUM_OFF, 0, 256 * sizeof(float), stream);
    hipMemcpyAsync(out + EMB_OFF, emb, (size_t)KCODES * CDIM * sizeof(float),
                   hipMemcpyDeviceToDevice, stream);

    prep_kernel<<<KCODES / 128, 128, 0, stream>>>(emb, Bpk, esq);
    score_kernel<<<NROWS / 128, 256, 0, stream>>>(in, Bpk, esq, emb, out, flag_list, flag_cnt, loss_acc);
    refine_kernel<<<1024, 128, 0, stream>>>(in, emb, esq, flag_list, flag_cnt, out, loss_acc);
    finalize_kernel<<<1, 1, 0, stream>>>(loss_acc, out);
}

// Round 7
// 209.829 us; speedup vs baseline: 1.1013x; 1.1013x over previous
//
#include <hip/hip_runtime.h>

// Problem geometry (fixed by the reference)
#define SPATIAL 32768            // D*H*W
#define NB 4
#define CDIM 128
#define KCODES 1024
#define NROWS (NB * SPATIAL)     // 131072

// Output layout in d_out (all float32, concatenated in return order)
#define Q_SIZE (NB * CDIM * SPATIAL)     // 16777216
#define LOSS_OFF Q_SIZE
#define IDX_OFF (Q_SIZE + 1)
#define ESUM_OFF (IDX_OFF + NROWS)
#define EMB_OFF (ESUM_OFF + 256)

#define TCODES 64                // codes per tile
#define NT (KCODES / TCODES)     // 16 tiles
#define MARGIN1 0.06f            // fp16 1-pass gap margin (~7.7 sigma)
#define MARGIN2 0.002f           // bf16 3-pass gap margin (~20 sigma)
#define CAP1 12288
#define CAP2 4096
#define FINF 3.4e38f
#define LSCALE 1048576.0f        // 2^20 fixed-point for deterministic loss

typedef _Float16 half8 __attribute__((ext_vector_type(8)));
typedef short short8 __attribute__((ext_vector_type(8)));
typedef float f32x4 __attribute__((ext_vector_type(4)));

static __device__ __forceinline__ unsigned short f2bf(float x) {
    unsigned u = __float_as_uint(x);
    unsigned r = (u + 0x7fffu + ((u >> 16) & 1u)) >> 16;   // RN-even
    return (unsigned short)r;
}
static __device__ __forceinline__ float bf2f(unsigned short h) {
    return __uint_as_float(((unsigned)h) << 16);
}

static __device__ __forceinline__ void gload16(const uint4* g, uint4* l) {
    __builtin_amdgcn_global_load_lds(
        (const __attribute__((address_space(1))) unsigned int*)g,
        (__attribute__((address_space(3))) unsigned int*)l, 16, 0, 0);
}

// ---- prep: emb -> fp16 tiles (Bpk16) + bf16 hi/lo tiles (Bpkbf) + ||e||^2 ---
// Bpk16 (uint4 of 8 fp16): [(t*64 + cl)*16 + (g ^ (cl&15))]
// Bpkbf (uint4 of 8 bf16): [t*2048 + hl*1024 + cl*16 + (g ^ (cl&15))]
__global__ __launch_bounds__(128) void prep_kernel(const float* __restrict__ emb,
                                                   uint4* __restrict__ Bpk16,
                                                   uint4* __restrict__ Bpkbf,
                                                   float* __restrict__ esq) {
    int k = blockIdx.x * 128 + threadIdx.x;
    if (k >= KCODES) return;
    int t = k >> 6, cl = k & 63;
    const float* e = emb + (size_t)k * CDIM;
    uint4* fp = Bpk16 + ((size_t)t * TCODES + cl) * 16;
    uint4* bh = Bpkbf + (size_t)t * 2048 + (size_t)cl * 16;
    uint4* bl = bh + 1024;
    float s = 0.f;
#pragma unroll
    for (int g = 0; g < 16; g++) {
        unsigned fpk[4], hp[4], lp[4];
#pragma unroll
        for (int p = 0; p < 4; p++) {
            float v0 = e[g * 8 + 2 * p + 0];
            float v1 = e[g * 8 + 2 * p + 1];
            union { _Float16 h[2]; unsigned u; } pk;
            pk.h[0] = (_Float16)v0; pk.h[1] = (_Float16)v1;
            fpk[p] = pk.u;
            unsigned short h0 = f2bf(v0), h1 = f2bf(v1);
            unsigned short l0 = f2bf(v0 - bf2f(h0)), l1 = f2bf(v1 - bf2f(h1));
            hp[p] = (unsigned)h0 | ((unsigned)h1 << 16);
            lp[p] = (unsigned)l0 | ((unsigned)l1 << 16);
            s = fmaf(v0, v0, s);
            s = fmaf(v1, v1, s);
        }
        int gp = g ^ (cl & 15);
        fp[gp] = make_uint4(fpk[0], fpk[1], fpk[2], fpk[3]);
        bh[gp] = make_uint4(hp[0], hp[1], hp[2], hp[3]);
        bl[gp] = make_uint4(lp[0], lp[1], lp[2], lp[3]);
    }
    esq[k] = s;
}

// ---- stage 1: fp16 single-pass scoring + fused emit (proven r5 structure) ---
__global__ __launch_bounds__(256, 3) void score_kernel(const float* __restrict__ in,
                                                       const uint4* __restrict__ Bpk,
                                                       const float* __restrict__ esq,
                                                       const float* __restrict__ emb,
                                                       float* __restrict__ out,
                                                       int* __restrict__ flag_list,
                                                       int* __restrict__ flag_cnt,
                                                       unsigned long long* __restrict__ loss_acc) {
    __shared__ uint4 BB[3][TCODES * 16];     // 3 x 16 KB ring
    __shared__ float b1L[128];
    __shared__ int   i1L[128];
    __shared__ float xsqL[128];
    __shared__ unsigned long long redL[16];

    const int tid = threadIdx.x;
    const int lane = tid & 63;
    const int w = tid >> 6;
    const int l15 = lane & 15;
    const int lg = lane >> 4;
    const int row0 = blockIdx.x * 128;
    const int b = row0 >> 15;
    const int sbase = (row0 & (SPATIAL - 1)) + w * 32;

#define STAGE(tt, bb)                                                     \
    do {                                                                  \
        const uint4* src_ = Bpk + (size_t)(tt) * 1024;                    \
        _Pragma("unroll")                                                 \
        for (int i_ = 0; i_ < 4; i_++)                                    \
            gload16(src_ + i_ * 256 + tid, &BB[bb][i_ * 256 + tid]);      \
    } while (0)

    STAGE(0, 0);
    STAGE(1, 1);

    half8 Af[8];
    float xsq[2] = {0.f, 0.f};
    {
        const float* xb = in + (size_t)b * CDIM * SPATIAL;
#pragma unroll
        for (int kk = 0; kk < 4; kk++)
#pragma unroll
            for (int m = 0; m < 2; m++) {
                int srow = sbase + m * 16 + l15;
                union { unsigned u[4]; half8 h; } pk;
#pragma unroll
                for (int p = 0; p < 4; p++) {
                    int c0 = kk * 32 + lg * 8 + 2 * p;
                    float v0 = xb[(size_t)(c0 + 0) * SPATIAL + srow];
                    float v1 = xb[(size_t)(c0 + 1) * SPATIAL + srow];
                    union { _Float16 h[2]; unsigned u; } q;
                    q.h[0] = (_Float16)v0; q.h[1] = (_Float16)v1;
                    pk.u[p] = q.u;
                    xsq[m] = fmaf(v0, v0, xsq[m]);
                    xsq[m] = fmaf(v1, v1, xsq[m]);
                }
                Af[kk * 2 + m] = pk.h;
            }
    }
#pragma unroll
    for (int m = 0; m < 2; m++) {
        xsq[m] += __shfl_xor(xsq[m], 16);
        xsq[m] += __shfl_xor(xsq[m], 32);
    }
    if (lg == 0) {
        xsqL[w * 32 + l15] = xsq[0];
        xsqL[w * 32 + 16 + l15] = xsq[1];
    }

    float b1[8], b2[8];
    int i1[8];
#pragma unroll
    for (int i = 0; i < 8; i++) { b1[i] = FINF; b2[i] = FINF; i1[i] = 0; }

    for (int t = 0; t < NT; t++) {
        if (t == NT - 1) asm volatile("s_waitcnt vmcnt(0)" ::: "memory");
        else             asm volatile("s_waitcnt vmcnt(4)" ::: "memory");
        __builtin_amdgcn_s_barrier();
        if (t + 2 < NT) STAGE(t + 2, (t + 2) % 3);

        const half8* Bs = reinterpret_cast<const half8*>(BB[t % 3]);
        f32x4 acc[2][4];
#pragma unroll
        for (int m = 0; m < 2; m++)
#pragma unroll
            for (int n = 0; n < 4; n++) acc[m][n] = (f32x4){0.f, 0.f, 0.f, 0.f};

#pragma unroll
        for (int kk = 0; kk < 4; kk++) {
            int phys = (kk * 4 + lg) ^ l15;
            half8 bv[4];
#pragma unroll
            for (int n = 0; n < 4; n++) bv[n] = Bs[(n * 16 + l15) * 16 + phys];
#pragma unroll
            for (int m = 0; m < 2; m++)
#pragma unroll
                for (int n = 0; n < 4; n++)
                    acc[m][n] = __builtin_amdgcn_mfma_f32_16x16x32_f16(Af[kk * 2 + m], bv[n], acc[m][n], 0, 0, 0);
        }

#pragma unroll
        for (int n = 0; n < 4; n++) {
            int col = t * TCODES + n * 16 + l15;
            float ev = esq[col];
#pragma unroll
            for (int m = 0; m < 2; m++)
#pragma unroll
                for (int r = 0; r < 4; r++) {
                    float sv = fmaf(-2.f, acc[m][n][r], ev);
                    int slot = m * 4 + r;
                    bool c = sv < b1[slot];
                    b2[slot] = fminf(fmaxf(sv, b1[slot]), b2[slot]);
                    b1[slot] = fminf(sv, b1[slot]);
                    i1[slot] = c ? col : i1[slot];
                }
        }
    }
#undef STAGE

#pragma unroll
    for (int j = 1; j < 16; j <<= 1) {
#pragma unroll
        for (int slot = 0; slot < 8; slot++) {
            float ob1 = __shfl_xor(b1[slot], j);
            float ob2 = __shfl_xor(b2[slot], j);
            int   oi  = __shfl_xor(i1[slot], j);
            bool take = (ob1 < b1[slot]) || (ob1 == b1[slot] && oi < i1[slot]);
            float nb2 = fminf(fmaxf(b1[slot], ob1), fminf(b2[slot], ob2));
            b1[slot] = take ? ob1 : b1[slot];
            i1[slot] = take ? oi : i1[slot];
            b2[slot] = nb2;
        }
    }

    __syncthreads();

    if (l15 == 0) {
        unsigned long long lsum = 0;
#pragma unroll
        for (int m = 0; m < 2; m++)
#pragma unroll
            for (int r = 0; r < 4; r++) {
                int slot = m * 4 + r;
                int rl = w * 32 + m * 16 + lg * 4 + r;
                b1L[rl] = b1[slot];
                i1L[rl] = i1[slot];
                float cexp = b1[slot] + xsqL[rl];
                unsigned long long ci = (unsigned long long)llrintf(cexp * LSCALE);
                if (b2[slot] - b1[slot] < MARGIN1) {
                    int p = atomicAdd(flag_cnt, 1);
                    if (p < CAP1) { flag_list[p] = row0 + rl; ci = 0; }
                }
                lsum += ci;
            }
        redL[w * 4 + lg] = lsum;
    }
    __syncthreads();
    if (tid == 0) {
        unsigned long long s = 0;
#pragma unroll
        for (int i = 0; i < 16; i++) s += redL[i];
        atomicAdd(loss_acc, s);
    }

    {
        const int rl = w * 32 + (lane & 31);
        const int row = row0 + rl;
        const int sp = (row0 & (SPATIAL - 1)) + rl;
        const int k = i1L[rl];
        const int chalf = lane >> 5;

        if (chalf == 0) out[IDX_OFF + row] = (float)k;
        const float4* ep = reinterpret_cast<const float4*>(emb + (size_t)k * CDIM + chalf * 64);
        float* qout = out + (size_t)b * CDIM * SPATIAL + (size_t)chalf * 64 * SPATIAL + sp;
#pragma unroll
        for (int i = 0; i < 16; i++) {
            float4 v = ep[i];
            qout[(size_t)(4 * i + 0) * SPATIAL] = v.x;
            qout[(size_t)(4 * i + 1) * SPATIAL] = v.y;
            qout[(size_t)(4 * i + 2) * SPATIAL] = v.z;
            qout[(size_t)(4 * i + 3) * SPATIAL] = v.w;
        }
    }
}

// ---- stage 2: bf16 3-pass MFMA rescan of flagged rows (gathered) ------------
__global__ __launch_bounds__(256, 2) void refine1_kernel(const float* __restrict__ in,
                                                         const uint4* __restrict__ Bpkbf,
                                                         const float* __restrict__ esq,
                                                         const float* __restrict__ emb,
                                                         float* __restrict__ out,
                                                         const int* __restrict__ flag_list,
                                                         const int* __restrict__ flag_cnt,
                                                         int* __restrict__ flag_list2,
                                                         int* __restrict__ flag_cnt2,
                                                         unsigned long long* __restrict__ loss_acc) {
    __shared__ uint4 BB[2048];       // 32 KB: one bf16 hi/lo tile of 64 codes
    __shared__ int   ridL[128];
    __shared__ float b1L[128];
    __shared__ int   i1L[128];
    __shared__ float xsqL[128];
    __shared__ int   defL[128];
    __shared__ unsigned long long redL[16];

    int n1 = *flag_cnt; if (n1 > CAP1) n1 = CAP1;
    const int base = blockIdx.x * 128;
    if (base >= n1) return;

    const int tid = threadIdx.x;
    const int lane = tid & 63;
    const int w = tid >> 6;
    const int l15 = lane & 15;
    const int lg = lane >> 4;

    if (tid < 128) {
        int fi = base + tid;
        ridL[tid] = (fi < n1) ? flag_list[fi] : -1;
    }
    __syncthreads();
    const int rid0 = ridL[0];

    // A fragments (gathered rows): bf16 hi/lo, all K=128; exact ||x||^2
    short8 Ah[8], Al[8];
    float xsq[2] = {0.f, 0.f};
#pragma unroll
    for (int kk = 0; kk < 4; kk++)
#pragma unroll
        for (int m = 0; m < 2; m++) {
            int rl = w * 32 + m * 16 + l15;
            int rid = ridL[rl]; if (rid < 0) rid = rid0;
            const float* xr = in + (size_t)(rid >> 15) * CDIM * SPATIAL + (rid & (SPATIAL - 1));
            unsigned hh[4], ll[4];
#pragma unroll
            for (int p = 0; p < 4; p++) {
                int c0 = kk * 32 + lg * 8 + 2 * p;
                float v0 = xr[(size_t)(c0 + 0) * SPATIAL];
                float v1 = xr[(size_t)(c0 + 1) * SPATIAL];
                unsigned short h0 = f2bf(v0), h1 = f2bf(v1);
                unsigned short l0 = f2bf(v0 - bf2f(h0)), l1 = f2bf(v1 - bf2f(h1));
                hh[p] = (unsigned)h0 | ((unsigned)h1 << 16);
                ll[p] = (unsigned)l0 | ((unsigned)l1 << 16);
                xsq[m] = fmaf(v0, v0, xsq[m]);
                xsq[m] = fmaf(v1, v1, xsq[m]);
            }
            union { unsigned u[4]; short8 s; } ch, cl2;
#pragma unroll
            for (int p = 0; p < 4; p++) { ch.u[p] = hh[p]; cl2.u[p] = ll[p]; }
            Ah[kk * 2 + m] = ch.s;
            Al[kk * 2 + m] = cl2.s;
        }
#pragma unroll
    for (int m = 0; m < 2; m++) {
        xsq[m] += __shfl_xor(xsq[m], 16);
        xsq[m] += __shfl_xor(xsq[m], 32);
    }
    if (lg == 0) {
        xsqL[w * 32 + l15] = xsq[0];
        xsqL[w * 32 + 16 + l15] = xsq[1];
    }

    float b1[8], b2[8];
    int i1[8];
#pragma unroll
    for (int i = 0; i < 8; i++) { b1[i] = FINF; b2[i] = FINF; i1[i] = 0; }

    const short8* BBs = reinterpret_cast<const short8*>(BB);

    for (int t = 0; t < NT; t++) {
        // stage tile t (2048 uint4, 8 per thread)
        const uint4* src = Bpkbf + (size_t)t * 2048;
#pragma unroll
        for (int i = 0; i < 8; i++)
            gload16(src + i * 256 + tid, &BB[i * 256 + tid]);
        __syncthreads();   // drains vmcnt

        f32x4 acc[2][4];
#pragma unroll
        for (int m = 0; m < 2; m++)
#pragma unroll
            for (int n = 0; n < 4; n++) acc[m][n] = (f32x4){0.f, 0.f, 0.f, 0.f};

#pragma unroll
        for (int kk = 0; kk < 4; kk++) {
            int phys = (kk * 4 + lg) ^ l15;
            short8 bh[4], bl[4];
#pragma unroll
            for (int n = 0; n < 4; n++) {
                int un = (n * 16 + l15) * 16 + phys;
                bh[n] = BBs[un];
                bl[n] = BBs[1024 + un];
            }
#pragma unroll
            for (int m = 0; m < 2; m++)
#pragma unroll
                for (int n = 0; n < 4; n++)
                    acc[m][n] = __builtin_amdgcn_mfma_f32_16x16x32_bf16(Ah[kk * 2 + m], bh[n], acc[m][n], 0, 0, 0);
#pragma unroll
            for (int m = 0; m < 2; m++)
#pragma unroll
                for (int n = 0; n < 4; n++)
                    acc[m][n] = __builtin_amdgcn_mfma_f32_16x16x32_bf16(Al[kk * 2 + m], bh[n], acc[m][n], 0, 0, 0);
#pragma unroll
            for (int m = 0; m < 2; m++)
#pragma unroll
                for (int n = 0; n < 4; n++)
                    acc[m][n] = __builtin_amdgcn_mfma_f32_16x16x32_bf16(Ah[kk * 2 + m], bl[n], acc[m][n], 0, 0, 0);
        }

#pragma unroll
        for (int n = 0; n < 4; n++) {
            int col = t * TCODES + n * 16 + l15;
            float ev = esq[col];
#pragma unroll
            for (int m = 0; m < 2; m++)
#pragma unroll
                for (int r = 0; r < 4; r++) {
                    float sv = fmaf(-2.f, acc[m][n][r], ev);
                    int slot = m * 4 + r;
                    bool c = sv < b1[slot];
                    b2[slot] = fminf(fmaxf(sv, b1[slot]), b2[slot]);
                    b1[slot] = fminf(sv, b1[slot]);
                    i1[slot] = c ? col : i1[slot];
                }
        }
        __syncthreads();   // before next tile overwrites BB
    }

#pragma unroll
    for (int j = 1; j < 16; j <<= 1) {
#pragma unroll
        for (int slot = 0; slot < 8; slot++) {
            float ob1 = __shfl_xor(b1[slot], j);
            float ob2 = __shfl_xor(b2[slot], j);
            int   oi  = __shfl_xor(i1[slot], j);
            bool take = (ob1 < b1[slot]) || (ob1 == b1[slot] && oi < i1[slot]);
            float nb2 = fminf(fmaxf(b1[slot], ob1), fminf(b2[slot], ob2));
            b1[slot] = take ? ob1 : b1[slot];
            i1[slot] = take ? oi : i1[slot];
            b2[slot] = nb2;
        }
    }

    if (l15 == 0) {
        unsigned long long lsum = 0;
#pragma unroll
        for (int m = 0; m < 2; m++)
#pragma unroll
            for (int r = 0; r < 4; r++) {
                int slot = m * 4 + r;
                int rl = w * 32 + m * 16 + lg * 4 + r;
                bool valid = (base + rl < n1);
                bool defer = (b2[slot] - b1[slot] < MARGIN2);
                b1L[rl] = b1[slot];
                i1L[rl] = i1[slot];
                defL[rl] = (!valid || defer) ? 1 : 0;
                if (valid) {
                    if (defer) {
                        int p = atomicAdd(flag_cnt2, 1);
                        if (p < CAP2) flag_list2[p] = ridL[rl];
                        else defL[rl] = 0;   // overflow: keep this stage's result
                    }
                    if (!defL[rl])
                        lsum += (unsigned long long)llrintf((b1[slot] + xsqL[rl]) * LSCALE);
                }
            }
        redL[w * 4 + lg] = lsum;
    }
    __syncthreads();
    if (tid == 0) {
        unsigned long long s = 0;
#pragma unroll
        for (int i = 0; i < 16; i++) s += redL[i];
        atomicAdd(loss_acc, s);
    }

    // emit idx + quantized for decided (valid, non-deferred) rows
    {
        const int rl = w * 32 + (lane & 31);
        if (base + rl < n1 && !defL[rl]) {
            const int rid = ridL[rl];
            const int bb = rid >> 15, sp = rid & (SPATIAL - 1);
            const int k = i1L[rl];
            const int chalf = lane >> 5;
            if (chalf == 0) out[IDX_OFF + rid] = (float)k;
            const float4* ep = reinterpret_cast<const float4*>(emb + (size_t)k * CDIM + chalf * 64);
            float* qout = out + (size_t)bb * CDIM * SPATIAL + (size_t)chalf * 64 * SPATIAL + sp;
#pragma unroll
            for (int i = 0; i < 16; i++) {
                float4 v = ep[i];
                qout[(size_t)(4 * i + 0) * SPATIAL] = v.x;
                qout[(size_t)(4 * i + 1) * SPATIAL] = v.y;
                qout[(size_t)(4 * i + 2) * SPATIAL] = v.z;
                qout[(size_t)(4 * i + 3) * SPATIAL] = v.w;
            }
        }
    }
}

// ---- stage 3: exact fp32 rescan of doubly-flagged rows (few hundred) --------
__global__ __launch_bounds__(256) void refine2_kernel(const float* __restrict__ in,
                                                      const float* __restrict__ emb,
                                                      const float* __restrict__ esq,
                                                      const int* __restrict__ flag_list2,
                                                      const int* __restrict__ flag_cnt2,
                                                      float* __restrict__ out,
                                                      unsigned long long* __restrict__ loss_acc) {
    __shared__ float xL[CDIM];
    __shared__ float rv[256];
    __shared__ int   ri[256];

    int n = *flag_cnt2; if (n > CAP2) n = CAP2;
    const int t = threadIdx.x;
    const float4* e4 = reinterpret_cast<const float4*>(emb);
    const float4* x4 = reinterpret_cast<const float4*>(xL);

    for (int fi = blockIdx.x; fi < n; fi += gridDim.x) {
        const int row = flag_list2[fi];
        const int b = row >> 15, s = row & (SPATIAL - 1);
        if (t < CDIM) xL[t] = in[((size_t)b * CDIM + t) * SPATIAL + s];
        __syncthreads();

        float best = FINF; int bi = 0;
#pragma unroll
        for (int j = 0; j < 4; j++) {
            const int k = j * 256 + t;
            float d0 = 0.f, d1 = 0.f, d2 = 0.f, d3 = 0.f;
#pragma unroll
            for (int c4 = 0; c4 < 32; c4++) {
                float4 ev = e4[(size_t)k * 32 + c4];
                float4 xx = x4[c4];
                d0 = fmaf(ev.x, xx.x, d0);
                d1 = fmaf(ev.y, xx.y, d1);
                d2 = fmaf(ev.z, xx.z, d2);
                d3 = fmaf(ev.w, xx.w, d3);
            }
            float d = fmaf(-2.f, (d0 + d1) + (d2 + d3), esq[k]);
            if (d < best) { best = d; bi = k; }
        }
        rv[t] = best; ri[t] = bi;
        __syncthreads();
#pragma unroll
        for (int off = 128; off > 0; off >>= 1) {
            if (t < off) {
                bool take = (rv[t + off] < rv[t]) ||
                            (rv[t + off] == rv[t] && ri[t + off] < ri[t]);
                if (take) { rv[t] = rv[t + off]; ri[t] = ri[t + off]; }
            }
            __syncthreads();
        }
        const int kbest = ri[0];
        const float dbest = rv[0];
        __syncthreads();

        rv[t] = (t < CDIM) ? xL[t] * xL[t] : 0.f;
        __syncthreads();
#pragma unroll
        for (int off = 128; off > 0; off >>= 1) {
            if (t < off) rv[t] += rv[t + off];
            __syncthreads();
        }
        if (t == 0) {
            out[IDX_OFF + row] = (float)kbest;
            atomicAdd(loss_acc, (unsigned long long)llrintf((dbest + rv[0]) * LSCALE));
        }
        if (t < CDIM)
            out[(size_t)b * CDIM * SPATIAL + (size_t)t * SPATIAL + s] = emb[(size_t)kbest * CDIM + t];
        __syncthreads();
    }
}

// ---- finalize: fixed-point -> float loss ------------------------------------
__global__ void finalize_kernel(const unsigned long long* __restrict__ loss_acc,
                                float* __restrict__ out) {
    double s = (double)*loss_acc / (double)LSCALE;
    out[LOSS_OFF] = (float)(0.25 * s / (double)Q_SIZE);
}

extern "C" void kernel_launch(void* const* d_in, const int* in_sizes, int n_in,
                              void* d_out, int out_size, void* d_ws, size_t ws_size,
                              hipStream_t stream) {
    const float* in = (const float*)d_in[0];
    const float* emb = (const float*)d_in[1];
    float* out = (float*)d_out;

    float* esq = (float*)d_ws;                                  // 4096 f32 (16 KB)
    uint4* Bpk16 = (uint4*)(esq + 4096);                        // 16384 uint4 (256 KB)
    uint4* Bpkbf = Bpk16 + 16384;                               // 32768 uint4 (512 KB)
    unsigned long long* loss_acc = (unsigned long long*)(Bpkbf + 32768);
    int* flag_cnt = (int*)(loss_acc + 2);
    int* flag_cnt2 = flag_cnt + 1;
    int* flag_list = flag_cnt2 + 3;                             // CAP1 i32
    int* flag_list2 = flag_list + CAP1;                         // CAP2 i32

    hipMemsetAsync(loss_acc, 0, 8, stream);
    hipMemsetAsync(flag_cnt, 0, 2 * sizeof(int), stream);
    hipMemsetAsync(out + ESUM_OFF, 0, 256 * sizeof(float), stream);
    hipMemcpyAsync(out + EMB_OFF, emb, (size_t)KCODES * CDIM * sizeof(float),
                   hipMemcpyDeviceToDevice, stream);

    prep_kernel<<<KCODES / 128, 128, 0, stream>>>(emb, Bpk16, Bpkbf, esq);
    score_kernel<<<NROWS / 128, 256, 0, stream>>>(in, Bpk16, esq, emb, out, flag_list, flag_cnt, loss_acc);
    refine1_kernel<<<CAP1 / 128, 256, 0, stream>>>(in, Bpkbf, esq, emb, out, flag_list, flag_cnt,
                                                   flag_list2, flag_cnt2, loss_acc);
    refine2_kernel<<<512, 256, 0, stream>>>(in, emb, esq, flag_list2, flag_cnt2, out, loss_acc);
    finalize_kernel<<<1, 1, 0, stream>>>(loss_acc, out);
}